// Round 17
// baseline (371.703 us; speedup 1.0000x reference)
//
#include <hip/hip_runtime.h>

namespace {

constexpr int Bn = 8192;
constexpr int Tn = 365;
constexpr int Hn = 34;
constexpr int GB = 16;      // batches per block -> grid 512, 2 blocks/CU
constexpr int NW = 9;       // waves per block: one MFMA tile each (tile 8 half-empty)
constexpr int NT = NW * 64; // 576 threads
constexpr int KP = 104;     // a_lds row stride in shorts (208 B = 52 words; 2-way banks)

constexpr float L2E = 1.44269504088896340736f;

typedef __attribute__((ext_vector_type(8))) short bf16x8;   // 8 bf16 = 4 VGPR
typedef __attribute__((ext_vector_type(4))) float f32x4;    // 16x16 MFMA acc

__device__ __forceinline__ float fexp2(float v) { return __builtin_amdgcn_exp2f(v); }
__device__ __forceinline__ float frcp(float v)  { return __builtin_amdgcn_rcpf(v); }

__device__ __forceinline__ unsigned short f2bf(float f) {   // RNE f32->bf16
    union { float f; unsigned u; } v; v.f = f;
    unsigned r = v.u + 0x7fffu + ((v.u >> 16) & 1u);
    return (unsigned short)(r >> 16);
}
__device__ __forceinline__ float bf2f(unsigned short s) {
    union { unsigned u; float f; } v; v.u = ((unsigned)s) << 16; return v.f;
}
__device__ __forceinline__ unsigned packh(float h) {
    unsigned short hh = f2bf(h);
    unsigned short hl = f2bf(h - bf2f(hh));
    return (unsigned)hh | ((unsigned)hl << 16);
}

// cross-wave LDS barrier WITHOUT a vmcnt drain: LDS writes drained (lgkmcnt),
// then raw s_barrier. Global stores/loads stay in flight across steps.
__device__ __forceinline__ void block_sync_lds() {
    __builtin_amdgcn_sched_barrier(0);
    asm volatile("s_waitcnt lgkmcnt(0)" ::: "memory");
    __builtin_amdgcn_s_barrier();
    __builtin_amdgcn_sched_barrier(0);
}

// K-layout (79 used of 96; pads stay zero). Weight rows PRE-SCALED by s(gate):
// -log2e (i,f,o) / +2*log2e (g)  =>  sigmoid = rcp(1+exp2(acc)),
// tanh = fma(-2, rcp(1+exp2(acc)), 1).
//   k=2j: h_h[j]<->bf16(s*w_hh[r][j]) ; k=2j+1: h_l[j]<->same
//   k68-70: x_h<->bf16(s*Wc) ; k71-73: x_l<->same ; k74-76: x_h<->residual
//   k77: 1.0<->bias_h ; k78: 1.0<->bias_l
//
// SWAPPED-OPERAND MFMA, ONE TILE PER WAVE (R17): D = W'(16 rhat x k) * data(k x 16 batch).
// Wave w owns global rows rhat = 16w .. 16w+15, i.e. cells 4w+0..3 (gate = rhat&3).
// C/D: col = lane&15 = batch, row = 4*(lane>>4)+reg = local rhat  ->  lane (kg,b)
// holds gates i,f,g,o of cell j0 = 4w+kg, batch b: update is LANE-LOCAL.
// Tile 8 (wave 8) covers cells 32,33 only (kg<2); wave 8 also stages x.
// 18 waves/CU (4.5/SIMD) vs R16's 8 — the latency-exposure fix.

__global__ __launch_bounds__(NT) void lstm_kernel(
    const float* __restrict__ x,      // [B,T,3]
    const float* __restrict__ fc0_w,  // [34,3]
    const float* __restrict__ fc0_b,  // [34]
    const float* __restrict__ w_ih,   // [136,34]
    const float* __restrict__ w_hh,   // [136,34]
    const float* __restrict__ b_ih,   // [136]
    const float* __restrict__ b_hh,   // [136]
    float* __restrict__ out)          // [B,T,34]
{
    __shared__ __align__(16) unsigned short a_lds[2][GB][KP]; // h/x operand, double-buffered

    const int tid  = threadIdx.x;
    const int lane = tid & 63;
    const int wv   = tid >> 6;      // wave id 0..8 = tile id
    const int b    = lane & 15;     // batch (D col); doubles as tile-row rho when building
    const int kg   = lane >> 4;     // k-group; D-row group

    // ---- one-time: this wave's weight A-fragments (1 tile x 3 K-chunks) ----
    // building: rho = b; global row = 16*wv + rho -> cell jl = 4*wv + (rho>>2), gate = rho&3
    bf16x8 Wt[3];
    {
        const int jl = 4 * wv + (b >> 2);
        const int g  = b & 3;
        const bool valid = (jl < Hn);
        const int r = g * Hn + (valid ? jl : 0);
        const float s = (g == 2) ? (2.f * L2E) : (-L2E);
        float wcv[3] = {0.f, 0.f, 0.f};
        float bia = 0.f;
        if (valid) {
            float ab = 0.f;
            for (int m = 0; m < Hn; ++m) {
                const float wi = w_ih[r * Hn + m];
                wcv[0] += wi * fc0_w[m * 3 + 0];
                wcv[1] += wi * fc0_w[m * 3 + 1];
                wcv[2] += wi * fc0_w[m * 3 + 2];
                ab     += wi * fc0_b[m];
            }
            wcv[0] *= s; wcv[1] *= s; wcv[2] *= s;
            bia = s * (ab + b_ih[r] + b_hh[r]);
        }
        #pragma unroll
        for (int ks = 0; ks < 3; ++ks) {
            bf16x8 f;
            #pragma unroll
            for (int e = 0; e < 8; ++e) {
                const int k = ks * 32 + kg * 8 + e;
                float val = 0.f;
                if (valid) {
                    if (k < 68)       val = s * w_hh[r * Hn + (k >> 1)];
                    else if (k < 71)  val = wcv[k - 68];
                    else if (k < 74)  val = wcv[k - 71];
                    else if (k < 77)  { const float w = wcv[k - 74]; val = w - bf2f(f2bf(w)); }
                    else if (k == 77) val = bia;                      // bias_h (x1.0 slot)
                    else if (k == 78) val = bia - bf2f(f2bf(bia));    // bias_l
                }
                f[e] = (short)f2bf(val);
            }
            Wt[ks] = f;
        }
    }

    // lane-local cell: j0 = 4*wv + kg (wave 8: 32+kg, valid only kg<2)
    const int j0 = 4 * wv + kg;
    const bool jval = (j0 < Hn);
    float c0 = 0.f, h0 = 0.f;

    // x staging: wave 8, lanes 0..47 (16 batches x 3 features)
    const bool xact = (wv == 8) && (lane < 48);
    const int bx = lane / 3;
    const int ix = lane - 3 * bx;

    // ---- zero both A buffers; barrier; bias-1.0 slots + x(0); barrier ----
    for (int i = tid; i < 2 * GB * KP; i += NT) ((unsigned short*)a_lds)[i] = 0;
    block_sync_lds();

    const long long bg = (long long)blockIdx.x * GB;
    const float* xblk = x + bg * (long long)(Tn * 3);
    float* oblk = out + bg * (long long)(Tn * Hn);
    const long long TH = (long long)Tn * Hn;

    if (tid < 32) {   // constant-1.0 slots (bias path), both buffers
        a_lds[tid >> 4][tid & 15][77] = (unsigned short)0x3F80;
        a_lds[tid >> 4][tid & 15][78] = (unsigned short)0x3F80;
    }
    if (xact) {
        const float xr = xblk[bx * (Tn * 3) + ix];
        const unsigned short xh = f2bf(xr);
        a_lds[0][bx][68 + ix] = xh;
        a_lds[0][bx][71 + ix] = f2bf(xr - bf2f(xh));
        a_lds[0][bx][74 + ix] = xh;
    }
    block_sync_lds();

    for (int t = 0; t < Tn; ++t) {
        const int cur = t & 1, nxt = cur ^ 1;

        // ---- top of step: global ops (fire-and-forget; retire under compute) ----
        if (t && jval)
            oblk[(long long)b * TH + (long long)(t - 1) * Hn + j0] = h0;
        float xr = 0.f;
        if (xact && t + 1 < Tn)
            xr = xblk[bx * (Tn * 3) + (t + 1) * 3 + ix];

        // ---- data B-fragments (row = batch = b) ----
        bf16x8 av[3];
        #pragma unroll
        for (int ks = 0; ks < 3; ++ks)
            av[ks] = *(const bf16x8*)(&a_lds[cur][b][ks * 32 + kg * 8]);

        // ---- MFMA: acc regs = gates i,f,g,o of cell j0, batch b ----
        f32x4 acc = {0.f, 0.f, 0.f, 0.f};
        #pragma unroll
        for (int ks = 0; ks < 3; ++ks)
            acc = __builtin_amdgcn_mfma_f32_16x16x32_bf16(Wt[ks], av[ks], acc, 0, 0, 0);

        // ---- lane-local nonlinearity + cell update ----
        if (jval) {
            const float gi = frcp(1.f + fexp2(acc[0]));
            const float gf = frcp(1.f + fexp2(acc[1]));
            const float gg = fmaf(-2.f, frcp(1.f + fexp2(acc[2])), 1.f);
            const float go = frcp(1.f + fexp2(acc[3]));
            c0 = gf * c0 + gi * gg;
            h0 = go * fmaf(-2.f, frcp(1.f + fexp2(c0 * (2.f * L2E))), 1.f);
            ((unsigned*)&a_lds[nxt][b][0])[j0] = packh(h0);
        }

        // ---- stage x(t+1) into next A buffer ----
        if (xact) {
            const unsigned short xh = f2bf(xr);
            a_lds[nxt][bx][68 + ix] = xh;
            a_lds[nxt][bx][71 + ix] = f2bf(xr - bf2f(xh));
            a_lds[nxt][bx][74 + ix] = xh;
        }

        block_sync_lds();   // the ONE sync/step: h(t) visible to all waves
    }

    // final store: h(Tn-1)
    if (jval)
        oblk[(long long)b * TH + (long long)(Tn - 1) * Hn + j0] = h0;
}

} // namespace

extern "C" void kernel_launch(void* const* d_in, const int* in_sizes, int n_in,
                              void* d_out, int out_size, void* d_ws, size_t ws_size,
                              hipStream_t stream) {
    const float* x     = (const float*)d_in[0];
    const float* fc0_w = (const float*)d_in[1];
    const float* fc0_b = (const float*)d_in[2];
    const float* w_ih  = (const float*)d_in[3];
    const float* w_hh  = (const float*)d_in[4];
    const float* b_ih  = (const float*)d_in[5];
    const float* b_hh  = (const float*)d_in[6];
    float* out = (float*)d_out;

    lstm_kernel<<<Bn / GB, NT, 0, stream>>>(x, fc0_w, fc0_b, w_ih, w_hh, b_ih, b_hh, out);
}

// Round 18
// 355.364 us; speedup vs baseline: 1.0460x; 1.0460x over previous
//
#include <hip/hip_runtime.h>

namespace {

constexpr int Bn = 8192;
constexpr int Tn = 365;
constexpr int Hn = 34;
constexpr int GB = 16;      // batches per block -> grid 512, 2 blocks/CU
constexpr int KP = 72;      // a_lds row stride in halves (144 B; 2-way banks)

constexpr float L2E = 1.44269504088896340736f;

typedef __attribute__((ext_vector_type(8))) _Float16 f16x8;  // 8 fp16 = 4 VGPR
typedef __attribute__((ext_vector_type(4))) float f32x4;     // 16x16 MFMA acc

__device__ __forceinline__ float fexp2(float v) { return __builtin_amdgcn_exp2f(v); }
__device__ __forceinline__ float frcp(float v)  { return __builtin_amdgcn_rcpf(v); }

// cross-wave LDS barrier WITHOUT a vmcnt drain: LDS writes drained (lgkmcnt),
// then raw s_barrier. Global stores/loads stay in flight across steps.
__device__ __forceinline__ void block_sync_lds() {
    __builtin_amdgcn_sched_barrier(0);
    asm volatile("s_waitcnt lgkmcnt(0)" ::: "memory");
    __builtin_amdgcn_s_barrier();
    __builtin_amdgcn_sched_barrier(0);
}

// FP16 K-layout (42 used of 64; pads stay zero). fp16 (e5m10): h,x,w all in
// [-5,5] mid-range -> 4x finer than bf16; fp16xfp16 products are EXACT in the
// f32 MFMA accumulate (11x11 <= 24 mantissa bits). No h hi/lo split needed.
// Weight rows PRE-SCALED by s(gate): -log2e (i,f,o) / +2*log2e (g):
//   sigmoid = rcp(1+exp2(acc)),  tanh = fma(-2, rcp(1+exp2(acc)), 1).
//   k 0-33 : h[j]   <-> fp16(s*w_hh[r][j])
//   k 34-36: x_h[i] <-> fp16(s*Wc[r][i])
//   k 37-39: x_l[i] <-> fp16(s*Wc[r][i])     (x_l = x - fp16(x): exact split)
//   k 40   : 1.0    <-> bias_h ;  k 41 : 1.0 <-> bias_l
//
// SWAPPED-OPERAND MFMA (from R16): D = W'(rhat x k) * data(k x batch).
// C/D: col = lane&15 = batch, row = 4*(lane>>4)+reg = rhat; rhat = 4*jl+gate
// -> lane (kg,b) holds gates i,f,g,o of cell jl = 4*tau+kg, batch b: the cell
// update is LANE-LOCAL. One raw s_barrier per step (h handoff only).

__global__ __launch_bounds__(256) void lstm_kernel(
    const float* __restrict__ x,      // [B,T,3]
    const float* __restrict__ fc0_w,  // [34,3]
    const float* __restrict__ fc0_b,  // [34]
    const float* __restrict__ w_ih,   // [136,34]
    const float* __restrict__ w_hh,   // [136,34]
    const float* __restrict__ b_ih,   // [136]
    const float* __restrict__ b_hh,   // [136]
    float* __restrict__ out)          // [B,T,34]
{
    __shared__ __align__(16) _Float16 a_lds[2][GB][KP]; // h/x operand, double-buffered

    const int tid  = threadIdx.x;
    const int lane = tid & 63;
    const int wv   = tid >> 6;      // wave id
    const int b    = lane & 15;     // batch (D col); tile-row rho when building W
    const int kg   = lane >> 4;     // k-group; D-row group

    // cell partition across waves: {9,9,8,8}
    const int nc   = (wv < 2) ? 9 : 8;
    const int base = (wv < 2) ? 9 * wv : 18 + 8 * (wv - 2);

    // ---- one-time: weight A-fragments (3 N-tiles x 2 K-chunks), prescaled fp16 ----
    f16x8 Wt[3][2];
    #pragma unroll
    for (int tau = 0; tau < 3; ++tau) {
        const int rhat = 16 * tau + b;
        const int jl = rhat >> 2, g = rhat & 3;
        const int r = (jl < nc) ? g * Hn + (base + jl) : -1;
        const float s = (g == 2) ? (2.f * L2E) : (-L2E);
        float swc[3] = {0.f, 0.f, 0.f};
        float bia = 0.f;
        if (r >= 0) {
            float ab = 0.f;
            for (int m = 0; m < Hn; ++m) {
                const float wi = w_ih[r * Hn + m];
                swc[0] += wi * fc0_w[m * 3 + 0];
                swc[1] += wi * fc0_w[m * 3 + 1];
                swc[2] += wi * fc0_w[m * 3 + 2];
                ab     += wi * fc0_b[m];
            }
            swc[0] *= s; swc[1] *= s; swc[2] *= s;
            bia = s * (ab + b_ih[r] + b_hh[r]);
        }
        #pragma unroll
        for (int ks = 0; ks < 2; ++ks) {
            f16x8 f;
            #pragma unroll
            for (int e = 0; e < 8; ++e) {
                const int k = ks * 32 + kg * 8 + e;
                float val = 0.f;
                if (r >= 0) {
                    if (k < 34)       val = s * w_hh[r * Hn + k];
                    else if (k < 37)  val = swc[k - 34];
                    else if (k < 40)  val = swc[k - 37];
                    else if (k == 40) val = bia;                          // bias_h
                    else if (k == 41) val = bia - (float)(_Float16)bia;   // bias_l
                }
                f[e] = (_Float16)val;
            }
            Wt[tau][ks] = f;
        }
    }

    // lane-local cells: jl = 4*tau + kg (tau=0,1 always valid; tau=2 iff 8+kg < nc)
    const bool has2 = (8 + kg < nc);
    float c0 = 0.f, c1 = 0.f, c2 = 0.f;
    float h0 = 0.f, h1 = 0.f, h2 = 0.f;

    // x staging: wave w stages batches 4w..4w+3 (12 lanes x 1 feature)
    const bool xact = (lane < 12);
    const int bx = 4 * wv + lane / 3;
    const int ix = lane - 3 * (lane / 3);

    // ---- zero both A buffers; barrier; bias-1.0 slots + x(0); barrier ----
    for (int i = tid; i < 2 * GB * KP; i += 256) ((_Float16*)a_lds)[i] = (_Float16)0.f;
    block_sync_lds();

    const long long bg = (long long)blockIdx.x * GB;
    const float* xblk = x + bg * (long long)(Tn * 3);
    float* oblk = out + bg * (long long)(Tn * Hn);
    const long long TH = (long long)Tn * Hn;

    if (tid < 32) {   // constant-1.0 slots (bias path), both buffers
        a_lds[tid >> 4][tid & 15][40] = (_Float16)1.f;
        a_lds[tid >> 4][tid & 15][41] = (_Float16)1.f;
    }
    if (xact) {
        const float xr = xblk[bx * (Tn * 3) + ix];
        const _Float16 xh = (_Float16)xr;
        a_lds[0][bx][34 + ix] = xh;
        a_lds[0][bx][37 + ix] = (_Float16)(xr - (float)xh);
    }
    block_sync_lds();

    // pointer-hoisted output cursor (stores h(t-1) at top of step t)
    float* pr = oblk + (long long)b * TH + base;

    for (int t = 0; t < Tn; ++t) {
        const int cur = t & 1, nxt = cur ^ 1;

        // ---- top of step: global ops (fire-and-forget; retire under compute) ----
        if (t) {
            pr[kg]     = h0;
            pr[4 + kg] = h1;
            if (has2) pr[8 + kg] = h2;
            pr += Hn;
        }
        float xr = 0.f;
        if (xact && t + 1 < Tn)
            xr = xblk[bx * (Tn * 3) + (t + 1) * 3 + ix];

        // ---- data B-fragments (row = batch = b): 2 x ds_read_b128 ----
        f16x8 av[2];
        #pragma unroll
        for (int ks = 0; ks < 2; ++ks)
            av[ks] = *(const f16x8*)(&a_lds[cur][b][ks * 32 + kg * 8]);

        // ---- MFMA (swapped): acc[tau] regs = gates i,f,g,o of cell 4*tau+kg ----
        f32x4 acc[3];
        #pragma unroll
        for (int tau = 0; tau < 3; ++tau) {
            acc[tau] = f32x4{0.f, 0.f, 0.f, 0.f};
            #pragma unroll
            for (int ks = 0; ks < 2; ++ks)
                acc[tau] = __builtin_amdgcn_mfma_f32_16x16x32_f16(Wt[tau][ks], av[ks], acc[tau], 0, 0, 0);
        }

        // ---- lane-local nonlinearity + cell update (gate = reg index, static) ----
        {
            const float gi = frcp(1.f + fexp2(acc[0][0]));
            const float gf = frcp(1.f + fexp2(acc[0][1]));
            const float gg = fmaf(-2.f, frcp(1.f + fexp2(acc[0][2])), 1.f);
            const float go = frcp(1.f + fexp2(acc[0][3]));
            c0 = gf * c0 + gi * gg;
            h0 = go * fmaf(-2.f, frcp(1.f + fexp2(c0 * (2.f * L2E))), 1.f);
            a_lds[nxt][b][base + kg] = (_Float16)h0;
        }
        {
            const float gi = frcp(1.f + fexp2(acc[1][0]));
            const float gf = frcp(1.f + fexp2(acc[1][1]));
            const float gg = fmaf(-2.f, frcp(1.f + fexp2(acc[1][2])), 1.f);
            const float go = frcp(1.f + fexp2(acc[1][3]));
            c1 = gf * c1 + gi * gg;
            h1 = go * fmaf(-2.f, frcp(1.f + fexp2(c1 * (2.f * L2E))), 1.f);
            a_lds[nxt][b][base + 4 + kg] = (_Float16)h1;
        }
        if (has2) {
            const float gi = frcp(1.f + fexp2(acc[2][0]));
            const float gf = frcp(1.f + fexp2(acc[2][1]));
            const float gg = fmaf(-2.f, frcp(1.f + fexp2(acc[2][2])), 1.f);
            const float go = frcp(1.f + fexp2(acc[2][3]));
            c2 = gf * c2 + gi * gg;
            h2 = go * fmaf(-2.f, frcp(1.f + fexp2(c2 * (2.f * L2E))), 1.f);
            a_lds[nxt][b][base + 8 + kg] = (_Float16)h2;
        }

        // ---- stage x(t+1) into next A buffer ----
        if (xact) {
            const _Float16 xh = (_Float16)xr;
            a_lds[nxt][bx][34 + ix] = xh;
            a_lds[nxt][bx][37 + ix] = (_Float16)(xr - (float)xh);
        }

        block_sync_lds();   // the ONE sync/step: h(t) visible to all waves
    }

    // final store: h(Tn-1)
    {
        pr[kg]     = h0;
        pr[4 + kg] = h1;
        if (has2) pr[8 + kg] = h2;
    }
}

} // namespace

extern "C" void kernel_launch(void* const* d_in, const int* in_sizes, int n_in,
                              void* d_out, int out_size, void* d_ws, size_t ws_size,
                              hipStream_t stream) {
    const float* x     = (const float*)d_in[0];
    const float* fc0_w = (const float*)d_in[1];
    const float* fc0_b = (const float*)d_in[2];
    const float* w_ih  = (const float*)d_in[3];
    const float* w_hh  = (const float*)d_in[4];
    const float* b_ih  = (const float*)d_in[5];
    const float* b_hh  = (const float*)d_in[6];
    float* out = (float*)d_out;

    lstm_kernel<<<Bn / GB, 256, 0, stream>>>(x, fc0_w, fc0_b, w_ih, w_hh, b_ih, b_hh, out);
}